// Round 11
// baseline (384.957 us; speedup 1.0000x reference)
//
#include <hip/hip_runtime.h>
#include <math.h>
#include <stdint.h>

// LSTMModel B=1024 T=512 D=32 H=64, 2 layers + fc1(relu) + fc2.
// Round 11: critical-path-minimized flag pipeline.
//   256 blocks x 4 batches; waves 0-3 = L0, 4-7 = L1 (4 tiles each).
//   DEP=8 slot rings for h0/h1. Per-wave u16 flags (no atomics): writer
//   stores flag after lgkmcnt(0); reader busy-spins on 2 packed dwords.
//   OFF-CHAIN MFMAs hoisted: L0 precomputes xpart(t+1) = bias + Wih0*x
//   in the shadow after its h0-write; L1 precomputes part(s+1) =
//   bias + Wih1*h0(s+1) in the shadow after its h1-write. Critical loop
//   per step = poll -> ds_read -> 2 dependent MFMA -> update -> write.
//   L0->L1 clobber guarded by s_pr1 (written AFTER L1's shadow read).

namespace {

constexpr int Hh = 64, Dd = 32, Tt = 512, DEP = 8;
constexpr float LOG2E = 1.4426950408889634f;

typedef _Float16 f16x8 __attribute__((ext_vector_type(8)));
typedef float f32x4 __attribute__((ext_vector_type(4)));

__device__ __forceinline__ f32x4 mfma(f16x8 a, f16x8 b, f32x4 c) {
    return __builtin_amdgcn_mfma_f32_16x16x32_f16(a, b, c, 0, 0, 0);
}
__device__ __forceinline__ float rcpf(float x) { return __builtin_amdgcn_rcpf(x); }
__device__ __forceinline__ float exp2f_(float x) { return __builtin_amdgcn_exp2f(x); }
__device__ __forceinline__ float sigm_s(float p) { return rcpf(1.0f + exp2f_(-p)); }
__device__ __forceinline__ float tanh_s(float p) {
    return 1.0f - 2.0f * rcpf(exp2f_(p) + 1.0f);
}
__device__ __forceinline__ float tanh_n(float c) {
    return 1.0f - 2.0f * rcpf(exp2f_(c * (2.0f * LOG2E)) + 1.0f);
}
__device__ __forceinline__ f16x8 cvt8s(const float* p, float sc) {
    f16x8 r;
#pragma unroll
    for (int e = 0; e < 8; ++e) r[e] = (_Float16)(p[e] * sc);
    return r;
}
__device__ __forceinline__ uint32_t umin_(uint32_t a, uint32_t b) {
    return a < b ? a : b;
}
__device__ __forceinline__ int min4u(uint32_t a, uint32_t b) {
    return (int)umin_(umin_(a & 0xffffu, a >> 16), umin_(b & 0xffffu, b >> 16));
}
// spin until min of 4 packed u16 flags >= tgt (tgt<=0 passes immediately)
__device__ __forceinline__ void pollflags(const unsigned short* f, int tgt) {
    const volatile uint32_t* p = (const volatile uint32_t*)f;
    for (;;) {
        const uint32_t a = p[0], b = p[1];
        if (min4u(a, b) >= tgt) break;
    }
    asm volatile("" ::: "memory");
}

__global__ __launch_bounds__(512, 2) void lstm_f16(
    const float* __restrict__ x,     // [B, T, D]
    const float* __restrict__ Wih0,  // [256, 32]
    const float* __restrict__ Whh0,  // [256, 64]
    const float* __restrict__ bih0, const float* __restrict__ bhh0,
    const float* __restrict__ Wih1,  // [256, 64]
    const float* __restrict__ Whh1,  // [256, 64]
    const float* __restrict__ bih1, const float* __restrict__ bhh1,
    const float* __restrict__ fc1w,  // [32, 64]
    const float* __restrict__ fc1b,  // [32]
    const float* __restrict__ fc2w,  // [1, 32]
    const float* __restrict__ fc2b,  // [1]
    float* __restrict__ out)         // [B]
{
    // slot rings: [slot][kfrag][row = kq*4 + col][e]; 256 f16 per slot
    __shared__ __align__(16) _Float16 s_h0[DEP][2][16][8];  // 4 KB
    __shared__ __align__(16) _Float16 s_h1[DEP][2][16][8];  // 4 KB
    __shared__ __align__(8) unsigned short s_f0[DEP][4];    // per-wave flags
    __shared__ __align__(8) unsigned short s_f1[DEP][4];
    __shared__ __align__(8) unsigned short s_pr1[4];        // L1 shadow progress
    __shared__ float s_hf[Hh][5];
    __shared__ float s_fcw[32 * 65];
    __shared__ float s_fc[32][5];

    const int tid = threadIdx.x;   // 0..511
    const int w = tid >> 6;        // wave 0..7
    const int l = tid & 63;
    const int ar = l & 15;         // A row within tile
    const int akb = l >> 4;        // k-group
    const int cq = l >> 4;         // C/D row block
    const int cj = l & 15;         // C/D col
    const int cb = cj & 3;         // real batch col
    const int dd = cj >> 2;        // tile select for update (0..3)
    const bool isL1w = (w >= 4);
    const int wl = w & 3;
    const int b0 = blockIdx.x * 4;

    // ---- persistent A fragments (log2e folded), 4 tiles x 4 k-slots ----
    const int r4 = ar & 3;
    const float sc = (r4 == 2) ? 2.0f * LOG2E : LOG2E;
    const int grow = r4 * 64 + 16 * wl + 4 * (ar >> 2);
    f16x8 Afr[4][4];
    if (!isL1w) {
#pragma unroll
        for (int i = 0; i < 4; ++i) {
            const int g = grow + i;
            Afr[i][0] = cvt8s(Wih0 + g * Dd + akb * 8, sc);       // x
            Afr[i][1] = cvt8s(Whh0 + g * Hh + akb * 8, sc);       // h0 k0-31
            Afr[i][2] = cvt8s(Whh0 + g * Hh + 32 + akb * 8, sc);  // h0 k32-63
            Afr[i][3] = Afr[i][1];                                 // unused
        }
    } else {
#pragma unroll
        for (int i = 0; i < 4; ++i) {
            const int g = grow + i;
            Afr[i][0] = cvt8s(Wih1 + g * Hh + akb * 8, sc);       // h0 k0-31
            Afr[i][1] = cvt8s(Wih1 + g * Hh + 32 + akb * 8, sc);  // h0 k32-63
            Afr[i][2] = cvt8s(Whh1 + g * Hh + akb * 8, sc);       // h1 k0-31
            Afr[i][3] = cvt8s(Whh1 + g * Hh + 32 + akb * 8, sc);  // h1 k32-63
        }
    }

    // bias as MFMA C-init
    const float* bi = isL1w ? bih1 : bih0;
    const float* bhp = isL1w ? bhh1 : bhh0;
    f32x4 biasT[4];
#pragma unroll
    for (int i = 0; i < 4; ++i)
#pragma unroll
        for (int r = 0; r < 4; ++r) {
            const float s2 = (r == 2) ? 2.0f * LOG2E : LOG2E;
            const int uu = 16 * wl + 4 * cq + i;
            biasT[i][r] = s2 * (bi[r * 64 + uu] + bhp[r * 64 + uu]);
        }

    // lane's update target: unit ub (its layer), col cb
    const int ub = 16 * wl + 4 * cq + dd;
    const int kf_h = ub >> 5;
    const int row_h = ((ub & 31) >> 3) * 4 + cb;
    const int e_h = ub & 7;
    _Float16* const wb = isL1w ? &s_h1[0][kf_h][row_h][e_h]
                               : &s_h0[0][kf_h][row_h][e_h];

    // b-frag read row: wrap col = l&3 (4-lane broadcast)
    const int rrow = (l >> 4) * 4 + (l & 3);
    const _Float16* const rb0 = &s_h0[0][0][rrow][0];
    const _Float16* const rb1 = &s_h1[0][0][rrow][0];

    // ---- init LDS ----
    {
        int* p0 = (int*)s_h0;
        int* p1 = (int*)s_h1;
        for (int i = tid; i < DEP * 128; i += 512) { p0[i] = 0; p1[i] = 0; }
        if (tid < DEP * 2) ((int*)s_f0)[tid] = 0;       // f0 + f1 (16 dwords)
        if (tid < 2) ((int*)s_pr1)[tid] = 0;
    }
    __syncthreads();

    if (!isL1w) {
        // =================== layer-0 waves ===================
        const float* xbase = x + ((size_t)(b0 + cb) * Tt) * Dd + akb * 8;
        float4 xra = *(const float4*)(xbase);
        float4 xrb = *(const float4*)(xbase + 4);
        f16x8 xcur;
#pragma unroll
        for (int e = 0; e < 4; ++e) {
            xcur[e] = (_Float16)xra[e];
            xcur[4 + e] = (_Float16)xrb[e];
        }
        xra = *(const float4*)(xbase + Dd);
        xrb = *(const float4*)(xbase + Dd + 4);

        f32x4 xpart[4];
#pragma unroll
        for (int i = 0; i < 4; ++i) xpart[i] = mfma(Afr[i][0], xcur, biasT[i]);

        float cst = 0.f;
        for (int t = 0; t < Tt; ++t) {
            const int rs = t & 7, ws = (t + 1) & 7;
            // critical: h0(t-1)
            pollflags(&s_f0[rs][0], t);
            const f16x8 b0a = *(const f16x8*)(rb0 + rs * 256);
            const f16x8 b0b = *(const f16x8*)(rb0 + rs * 256 + 128);
            // early-issue backpressure read (checked before write)
            const volatile uint32_t* bp = (const volatile uint32_t*)&s_pr1[0];
            const uint32_t bpa = bp[0], bpb = bp[1];

            f32x4 acc[4];
#pragma unroll
            for (int i = 0; i < 4; ++i) {
                f32x4 a = mfma(Afr[i][1], b0a, xpart[i]);
                acc[i] = mfma(Afr[i][2], b0b, a);
            }
            const f32x4 g01 = (dd & 1) ? acc[1] : acc[0];
            const f32x4 g23 = (dd & 1) ? acc[3] : acc[2];
            const f32x4 gg = (dd & 2) ? g23 : g01;
            const float gi = sigm_s(gg[0]);
            const float gf = sigm_s(gg[1]);
            const float zz = tanh_s(gg[2]);
            const float go = sigm_s(gg[3]);
            cst = gf * cst + gi * zz;
            const float hv = go * tanh_n(cst);

            // backpressure: slot ws holds h0(t-7); L1 shadow must be done
            if (min4u(bpa, bpb) < t - 7) pollflags(&s_pr1[0], t - 7);
            wb[ws * 256] = (_Float16)hv;
            asm volatile("s_waitcnt lgkmcnt(0)" ::: "memory");
            if (l == 0) s_f0[ws][wl] = (unsigned short)(t + 1);

            // shadow: xpart(t+1), x prefetch depth-2
            f16x8 xn;
#pragma unroll
            for (int e = 0; e < 4; ++e) {
                xn[e] = (_Float16)xra[e];
                xn[4 + e] = (_Float16)xrb[e];
            }
            const int tf = (t + 2 < Tt) ? (t + 2) : (Tt - 1);
            xra = *(const float4*)(xbase + (size_t)tf * Dd);
            xrb = *(const float4*)(xbase + (size_t)tf * Dd + 4);
            xcur = xn;
#pragma unroll
            for (int i = 0; i < 4; ++i) xpart[i] = mfma(Afr[i][0], xcur, biasT[i]);
        }
    } else {
        // =================== layer-1 waves ===================
        f32x4 part[4];
        {   // prologue: part(0) = bias + Wih1 * h0(0)   (slot 1, flag >= 1)
            pollflags(&s_f0[1][0], 1);
            const f16x8 a0 = *(const f16x8*)(rb0 + 1 * 256);
            const f16x8 a1 = *(const f16x8*)(rb0 + 1 * 256 + 128);
#pragma unroll
            for (int i = 0; i < 4; ++i) {
                f32x4 p = mfma(Afr[i][0], a0, biasT[i]);
                part[i] = mfma(Afr[i][1], a1, p);
            }
        }
        float cst = 0.f, lasth = 0.f;
        for (int s = 0; s < Tt; ++s) {
            const int rs = s & 7, ws = (s + 1) & 7;
            // critical: h1(s-1)
            pollflags(&s_f1[rs][0], s);
            const f16x8 b1a = *(const f16x8*)(rb1 + rs * 256);
            const f16x8 b1b = *(const f16x8*)(rb1 + rs * 256 + 128);
            f32x4 acc[4];
#pragma unroll
            for (int i = 0; i < 4; ++i) {
                f32x4 a = mfma(Afr[i][2], b1a, part[i]);
                acc[i] = mfma(Afr[i][3], b1b, a);
            }
            const f32x4 g01 = (dd & 1) ? acc[1] : acc[0];
            const f32x4 g23 = (dd & 1) ? acc[3] : acc[2];
            const f32x4 gg = (dd & 2) ? g23 : g01;
            const float gi = sigm_s(gg[0]);
            const float gf = sigm_s(gg[1]);
            const float zz = tanh_s(gg[2]);
            const float go = sigm_s(gg[3]);
            cst = gf * cst + gi * zz;
            const float hv = go * tanh_n(cst);
            lasth = hv;

            wb[ws * 256] = (_Float16)hv;   // h1(s) -> slot (s+1)%8
            asm volatile("s_waitcnt lgkmcnt(0)" ::: "memory");
            if (l == 0) s_f1[ws][wl] = (unsigned short)(s + 1);

            // shadow: part(s+1) = bias + Wih1 * h0(s+1); then progress flag
            if (s + 1 < Tt) {
                const int r0 = (s + 2) & 7;
                pollflags(&s_f0[r0][0], s + 2);
                const f16x8 a0 = *(const f16x8*)(rb0 + r0 * 256);
                const f16x8 a1 = *(const f16x8*)(rb0 + r0 * 256 + 128);
#pragma unroll
                for (int i = 0; i < 4; ++i) {
                    f32x4 p = mfma(Afr[i][0], a0, biasT[i]);
                    part[i] = mfma(Afr[i][1], a1, p);
                }
                asm volatile("s_waitcnt lgkmcnt(0)" ::: "memory");
                if (l == 0) s_pr1[wl] = (unsigned short)(s + 1);
            }
        }
        s_hf[ub][cb] = lasth;  // h1(511)
    }
    __syncthreads();

    // ---- FC epilogue (4 batches) ----
    for (int i2 = tid; i2 < 32 * 64; i2 += 512) {
        const int m = i2 >> 6, uu = i2 & 63;
        s_fcw[m * 65 + uu] = fc1w[i2];
    }
    __syncthreads();
    if (tid < 128) {
        const int m = tid >> 2, jj = tid & 3;
        float acc = fc1b[m];
#pragma unroll
        for (int uu = 0; uu < Hh; ++uu)
            acc = fmaf(s_fcw[m * 65 + uu], s_hf[uu][jj], acc);
        s_fc[m][jj] = fmaxf(acc, 0.f);
    }
    __syncthreads();
    if (tid < 4) {
        float acc = fc2b[0];
#pragma unroll
        for (int m = 0; m < 32; ++m)
            acc = fmaf(fc2w[m], s_fc[m][tid], acc);
        out[b0 + tid] = acc;
    }
}

}  // namespace

extern "C" void kernel_launch(void* const* d_in, const int* in_sizes, int n_in,
                              void* d_out, int out_size, void* d_ws, size_t ws_size,
                              hipStream_t stream) {
    const float* x    = (const float*)d_in[0];
    const float* Wih0 = (const float*)d_in[1];
    const float* Whh0 = (const float*)d_in[2];
    const float* bih0 = (const float*)d_in[3];
    const float* bhh0 = (const float*)d_in[4];
    const float* Wih1 = (const float*)d_in[5];
    const float* Whh1 = (const float*)d_in[6];
    const float* bih1 = (const float*)d_in[7];
    const float* bhh1 = (const float*)d_in[8];
    const float* fc1w = (const float*)d_in[9];
    const float* fc1b = (const float*)d_in[10];
    const float* fc2w = (const float*)d_in[11];
    const float* fc2b = (const float*)d_in[12];
    float* out = (float*)d_out;

    lstm_f16<<<dim3(256), dim3(512), 0, stream>>>(
        x, Wih0, Whh0, bih0, bhh0, Wih1, Whh1, bih1, bhh1,
        fc1w, fc1b, fc2w, fc2b, out);
}

// Round 12
// 370.976 us; speedup vs baseline: 1.0377x; 1.0377x over previous
//
#include <hip/hip_runtime.h>
#include <math.h>
#include <stdint.h>

// LSTMModel B=1024 T=512 D=32 H=64, 2 layers + fc1(relu) + fc2.
// Round 12: short-critical-path flag pipeline WITH slack (fixes R11).
//   256 blocks x 4 batches; waves 0-3 = L0, 4-7 = L1 (4 tiles each).
//   DEP=8 rings. Per-wave u16 flags; expected-pass polls (sleep only on
//   miss). L1 starts after L0 lead >= 4; lead self-stabilizes in [2,8]:
//   L1 prefetches h0(s+1) to REGS during step s (needs lead>=2); L0
//   backpressure (biased progress s+8, gated t>=8) binds at lead 8.
//   Off-chain MFMAs hoisted: L0's xpart in shadow, L1's Wih1-part from
//   prefetched regs. Critical loop = poll -> ds_read -> 2x4 dependent
//   MFMA -> act -> write -> flag. Unroll 8 (slots compile-time).

namespace {

constexpr int Hh = 64, Dd = 32, Tt = 512, DEP = 8;
constexpr float LOG2E = 1.4426950408889634f;

typedef _Float16 f16x8 __attribute__((ext_vector_type(8)));
typedef float f32x4 __attribute__((ext_vector_type(4)));

__device__ __forceinline__ f32x4 mfma(f16x8 a, f16x8 b, f32x4 c) {
    return __builtin_amdgcn_mfma_f32_16x16x32_f16(a, b, c, 0, 0, 0);
}
__device__ __forceinline__ float rcpf(float x) { return __builtin_amdgcn_rcpf(x); }
__device__ __forceinline__ float exp2f_(float x) { return __builtin_amdgcn_exp2f(x); }
__device__ __forceinline__ float sigm_s(float p) { return rcpf(1.0f + exp2f_(-p)); }
__device__ __forceinline__ float tanh_s(float p) {
    return 1.0f - 2.0f * rcpf(exp2f_(p) + 1.0f);
}
__device__ __forceinline__ float tanh_n(float c) {
    return 1.0f - 2.0f * rcpf(exp2f_(c * (2.0f * LOG2E)) + 1.0f);
}
__device__ __forceinline__ f16x8 cvt8s(const float* p, float sc) {
    f16x8 r;
#pragma unroll
    for (int e = 0; e < 8; ++e) r[e] = (_Float16)(p[e] * sc);
    return r;
}
__device__ __forceinline__ uint32_t umin_(uint32_t a, uint32_t b) {
    return a < b ? a : b;
}
__device__ __forceinline__ int min4u(uint32_t a, uint32_t b) {
    return (int)umin_(umin_(a & 0xffffu, a >> 16), umin_(b & 0xffffu, b >> 16));
}
// expected-pass wait: 1 probe, sleep-spin only on miss
__device__ __forceinline__ void waitflags(const unsigned short* f, int tgt) {
    const volatile uint32_t* p = (const volatile uint32_t*)f;
    if (min4u(p[0], p[1]) < tgt) {
        do { __builtin_amdgcn_s_sleep(1); } while (min4u(p[0], p[1]) < tgt);
    }
    asm volatile("" ::: "memory");
}

__global__ __launch_bounds__(512, 2) void lstm_f16(
    const float* __restrict__ x,     // [B, T, D]
    const float* __restrict__ Wih0,  // [256, 32]
    const float* __restrict__ Whh0,  // [256, 64]
    const float* __restrict__ bih0, const float* __restrict__ bhh0,
    const float* __restrict__ Wih1,  // [256, 64]
    const float* __restrict__ Whh1,  // [256, 64]
    const float* __restrict__ bih1, const float* __restrict__ bhh1,
    const float* __restrict__ fc1w,  // [32, 64]
    const float* __restrict__ fc1b,  // [32]
    const float* __restrict__ fc2w,  // [1, 32]
    const float* __restrict__ fc2b,  // [1]
    float* __restrict__ out)         // [B]
{
    // slot rings: [slot][kfrag][row = kq*4 + col][e]; 256 f16 per slot
    __shared__ __align__(16) _Float16 s_h0[DEP][2][16][8];  // 4 KB
    __shared__ __align__(16) _Float16 s_h1[DEP][2][16][8];  // 4 KB
    __shared__ __align__(8) unsigned short s_f0[DEP][4];
    __shared__ __align__(8) unsigned short s_f1[DEP][4];
    __shared__ __align__(8) unsigned short s_pr1[4];  // L1 progress, biased +8
    __shared__ float s_hf[Hh][5];
    __shared__ float s_fcw[32 * 65];
    __shared__ float s_fc[32][5];

    const int tid = threadIdx.x;   // 0..511
    const int w = tid >> 6;        // wave 0..7
    const int l = tid & 63;
    const int ar = l & 15;
    const int akb = l >> 4;
    const int cq = l >> 4;
    const int cj = l & 15;
    const int cb = cj & 3;
    const int dd = cj >> 2;
    const bool isL1w = (w >= 4);
    const int wl = w & 3;
    const int b0 = blockIdx.x * 4;

    // ---- persistent A fragments (log2e folded), 4 tiles x 4 k-slots ----
    const int r4 = ar & 3;
    const float sc = (r4 == 2) ? 2.0f * LOG2E : LOG2E;
    const int grow = r4 * 64 + 16 * wl + 4 * (ar >> 2);
    f16x8 Afr[4][4];
    if (!isL1w) {
#pragma unroll
        for (int i = 0; i < 4; ++i) {
            const int g = grow + i;
            Afr[i][0] = cvt8s(Wih0 + g * Dd + akb * 8, sc);       // x
            Afr[i][1] = cvt8s(Whh0 + g * Hh + akb * 8, sc);       // h0 k0-31
            Afr[i][2] = cvt8s(Whh0 + g * Hh + 32 + akb * 8, sc);  // h0 k32-63
            Afr[i][3] = Afr[i][1];
        }
    } else {
#pragma unroll
        for (int i = 0; i < 4; ++i) {
            const int g = grow + i;
            Afr[i][0] = cvt8s(Wih1 + g * Hh + akb * 8, sc);       // h0 k0-31
            Afr[i][1] = cvt8s(Wih1 + g * Hh + 32 + akb * 8, sc);  // h0 k32-63
            Afr[i][2] = cvt8s(Whh1 + g * Hh + akb * 8, sc);       // h1 k0-31
            Afr[i][3] = cvt8s(Whh1 + g * Hh + 32 + akb * 8, sc);  // h1 k32-63
        }
    }

    const float* bi = isL1w ? bih1 : bih0;
    const float* bhp = isL1w ? bhh1 : bhh0;
    f32x4 biasT[4];
#pragma unroll
    for (int i = 0; i < 4; ++i)
#pragma unroll
        for (int r = 0; r < 4; ++r) {
            const float s2 = (r == 2) ? 2.0f * LOG2E : LOG2E;
            const int uu = 16 * wl + 4 * cq + i;
            biasT[i][r] = s2 * (bi[r * 64 + uu] + bhp[r * 64 + uu]);
        }

    const int ub = 16 * wl + 4 * cq + dd;
    const int kf_h = ub >> 5;
    const int row_h = ((ub & 31) >> 3) * 4 + cb;
    const int e_h = ub & 7;
    _Float16* const wb = isL1w ? &s_h1[0][kf_h][row_h][e_h]
                               : &s_h0[0][kf_h][row_h][e_h];

    const int rrow = (l >> 4) * 4 + (l & 3);
    const _Float16* const rb0 = &s_h0[0][0][rrow][0];
    const _Float16* const rb1 = &s_h1[0][0][rrow][0];

    // ---- init LDS ----
    {
        int* p0 = (int*)s_h0;
        int* p1 = (int*)s_h1;
#pragma unroll
        for (int k = 0; k < DEP * 128 / 512; ++k) {
            p0[tid + 512 * k] = 0;
            p1[tid + 512 * k] = 0;
        }
        if (tid < DEP * 2) ((int*)s_f0)[tid] = 0;  // covers s_f0 + s_f1
        if (tid < 2) ((int*)s_pr1)[tid] = 0;
    }
    __syncthreads();

    if (!isL1w) {
        // =================== layer-0 waves ===================
        const float* xbase = x + ((size_t)(b0 + cb) * Tt) * Dd + akb * 8;
        float4 xra = *(const float4*)(xbase);
        float4 xrb = *(const float4*)(xbase + 4);
        f16x8 xcur;
#pragma unroll
        for (int e = 0; e < 4; ++e) {
            xcur[e] = (_Float16)xra[e];
            xcur[4 + e] = (_Float16)xrb[e];
        }
        xra = *(const float4*)(xbase + Dd);
        xrb = *(const float4*)(xbase + Dd + 4);

        f32x4 xpart[4];
#pragma unroll
        for (int i = 0; i < 4; ++i) xpart[i] = mfma(Afr[i][0], xcur, biasT[i]);

        float cst = 0.f;
#pragma unroll 8
        for (int t = 0; t < Tt; ++t) {
            const int rs = t & 7, ws = (t + 1) & 7;
            // critical: h0(t-1)
            waitflags(&s_f0[rs][0], t);
            const f16x8 b0a = *(const f16x8*)(rb0 + rs * 256);
            const f16x8 b0b = *(const f16x8*)(rb0 + rs * 256 + 128);
            // early-issue backpressure probe
            const volatile uint32_t* bp = (const volatile uint32_t*)&s_pr1[0];
            uint32_t bpa = 0, bpb = 0;
            if (t >= 8) { bpa = bp[0]; bpb = bp[1]; }

            f32x4 acc[4];
#pragma unroll
            for (int i = 0; i < 4; ++i) {
                f32x4 a = mfma(Afr[i][1], b0a, xpart[i]);
                acc[i] = mfma(Afr[i][2], b0b, a);
            }
            const f32x4 g01 = (dd & 1) ? acc[1] : acc[0];
            const f32x4 g23 = (dd & 1) ? acc[3] : acc[2];
            const f32x4 gg = (dd & 2) ? g23 : g01;
            const float gi = sigm_s(gg[0]);
            const float gf = sigm_s(gg[1]);
            const float zz = tanh_s(gg[2]);
            const float go = sigm_s(gg[3]);
            cst = gf * cst + gi * zz;
            const float hv = go * tanh_n(cst);

            // backpressure: clobbering h0(t-7); need L1 progress (s+8) >= t
            if (t >= 8 && min4u(bpa, bpb) < t) waitflags(&s_pr1[0], t);
            wb[ws * 256] = (_Float16)hv;
            asm volatile("s_waitcnt lgkmcnt(0)" ::: "memory");
            if (l == 0) s_f0[ws][wl] = (unsigned short)(t + 1);

            // shadow: xpart(t+1), x prefetch depth-2
            f16x8 xn;
#pragma unroll
            for (int e = 0; e < 4; ++e) {
                xn[e] = (_Float16)xra[e];
                xn[4 + e] = (_Float16)xrb[e];
            }
            const int tf = (t + 2 < Tt) ? (t + 2) : (Tt - 1);
            xra = *(const float4*)(xbase + (size_t)tf * Dd);
            xrb = *(const float4*)(xbase + (size_t)tf * Dd + 4);
            xcur = xn;
#pragma unroll
            for (int i = 0; i < 4; ++i)
                xpart[i] = mfma(Afr[i][0], xcur, biasT[i]);
        }
    } else {
        // =================== layer-1 waves ===================
        // startup slack: wait until L0 has finished step 3 (lead >= 4)
        waitflags(&s_f0[4][0], 4);
        // prefetch h0(0) from slot 1 (flag 1 <= 4, already published)
        f16x8 h0a = *(const f16x8*)(rb0 + 1 * 256);
        f16x8 h0b = *(const f16x8*)(rb0 + 1 * 256 + 128);

        float cst = 0.f, lasth = 0.f;
#pragma unroll 8
        for (int s = 0; s < Tt; ++s) {
            const int rs = s & 7, ws = (s + 1) & 7;
            // off-chain: part(s) from prefetched h0(s) regs
            f32x4 part[4];
#pragma unroll
            for (int i = 0; i < 4; ++i) {
                f32x4 p = mfma(Afr[i][0], h0a, biasT[i]);
                part[i] = mfma(Afr[i][1], h0b, p);
            }
            // critical: h1(s-1)
            waitflags(&s_f1[rs][0], s);
            const f16x8 b1a = *(const f16x8*)(rb1 + rs * 256);
            const f16x8 b1b = *(const f16x8*)(rb1 + rs * 256 + 128);
            f32x4 acc[4];
#pragma unroll
            for (int i = 0; i < 4; ++i) {
                f32x4 a = mfma(Afr[i][2], b1a, part[i]);
                acc[i] = mfma(Afr[i][3], b1b, a);
            }
            const f32x4 g01 = (dd & 1) ? acc[1] : acc[0];
            const f32x4 g23 = (dd & 1) ? acc[3] : acc[2];
            const f32x4 gg = (dd & 2) ? g23 : g01;
            const float gi = sigm_s(gg[0]);
            const float gf = sigm_s(gg[1]);
            const float zz = tanh_s(gg[2]);
            const float go = sigm_s(gg[3]);
            cst = gf * cst + gi * zz;
            const float hv = go * tanh_n(cst);
            lasth = hv;

            wb[ws * 256] = (_Float16)hv;   // h1(s) -> slot (s+1)&7
            asm volatile("s_waitcnt lgkmcnt(0)" ::: "memory");
            if (l == 0) s_f1[ws][wl] = (unsigned short)(s + 1);

            // prefetch h0(s+1) from slot (s+2)&7 (needs L0 lead >= 2)
            if (s + 1 < Tt) {
                const int r0 = (s + 2) & 7;
                waitflags(&s_f0[r0][0], s + 2);
                h0a = *(const f16x8*)(rb0 + r0 * 256);
                h0b = *(const f16x8*)(rb0 + r0 * 256 + 128);
                asm volatile("s_waitcnt lgkmcnt(0)" ::: "memory");
            }
            // progress (biased +8): h0 consumed through s+1
            if (l == 0) s_pr1[wl] = (unsigned short)(s + 8);
        }
        s_hf[ub][cb] = lasth;  // h1(511)
    }
    __syncthreads();

    // ---- FC epilogue (4 batches) ----
    for (int i2 = tid; i2 < 32 * 64; i2 += 512) {
        const int m = i2 >> 6, uu = i2 & 63;
        s_fcw[m * 65 + uu] = fc1w[i2];
    }
    __syncthreads();
    if (tid < 128) {
        const int m = tid >> 2, jj = tid & 3;
        float acc = fc1b[m];
#pragma unroll
        for (int uu = 0; uu < Hh; ++uu)
            acc = fmaf(s_fcw[m * 65 + uu], s_hf[uu][jj], acc);
        s_fc[m][jj] = fmaxf(acc, 0.f);
    }
    __syncthreads();
    if (tid < 4) {
        float acc = fc2b[0];
#pragma unroll
        for (int m = 0; m < 32; ++m)
            acc = fmaf(fc2w[m], s_fc[m][tid], acc);
        out[b0 + tid] = acc;
    }
}

}  // namespace

extern "C" void kernel_launch(void* const* d_in, const int* in_sizes, int n_in,
                              void* d_out, int out_size, void* d_ws, size_t ws_size,
                              hipStream_t stream) {
    const float* x    = (const float*)d_in[0];
    const float* Wih0 = (const float*)d_in[1];
    const float* Whh0 = (const float*)d_in[2];
    const float* bih0 = (const float*)d_in[3];
    const float* bhh0 = (const float*)d_in[4];
    const float* Wih1 = (const float*)d_in[5];
    const float* Whh1 = (const float*)d_in[6];
    const float* bih1 = (const float*)d_in[7];
    const float* bhh1 = (const float*)d_in[8];
    const float* fc1w = (const float*)d_in[9];
    const float* fc1b = (const float*)d_in[10];
    const float* fc2w = (const float*)d_in[11];
    const float* fc2b = (const float*)d_in[12];
    float* out = (float*)d_out;

    lstm_f16<<<dim3(256), dim3(512), 0, stream>>>(
        x, Wih0, Whh0, bih0, bhh0, Wih1, Whh1, bih1, bhh1,
        fc1w, fc1b, fc2w, fc2b, out);
}

// Round 13
// 290.362 us; speedup vs baseline: 1.3258x; 1.2776x over previous
//
#include <hip/hip_runtime.h>
#include <math.h>
#include <stdint.h>

// LSTMModel B=1024 T=512 D=32 H=64, 2 layers + fc1(relu) + fc2.
// Round 13: R7 skeleton (256 blocks x 4 batches, layer-split waves, dup-free
//   h frags, 1 lgkm-only barrier/step) with chain trims:
//   (1) crit/part accumulator split: h1-dep chain = 2 MFMA + add (was 4);
//   (2) h tail via fma(-2*go, rcp(...), go);
//   (3) LDS stagger: L1 reads issue first post-barrier, L0 does x VALU first.

namespace {

constexpr int Hh = 64, Dd = 32, Tt = 512;
constexpr float LOG2E = 1.4426950408889634f;

typedef _Float16 f16x8 __attribute__((ext_vector_type(8)));
typedef float f32x4 __attribute__((ext_vector_type(4)));

__device__ __forceinline__ f32x4 mfma(f16x8 a, f16x8 b, f32x4 c) {
    return __builtin_amdgcn_mfma_f32_16x16x32_f16(a, b, c, 0, 0, 0);
}
__device__ __forceinline__ float rcpf(float x) { return __builtin_amdgcn_rcpf(x); }
__device__ __forceinline__ float exp2f_(float x) { return __builtin_amdgcn_exp2f(x); }
__device__ __forceinline__ float sigm_s(float p) { return rcpf(1.0f + exp2f_(-p)); }
__device__ __forceinline__ float tanh_s(float p) {
    return 1.0f - 2.0f * rcpf(exp2f_(p) + 1.0f);
}
__device__ __forceinline__ f16x8 cvt8s(const float* p, float sc) {
    f16x8 r;
#pragma unroll
    for (int e = 0; e < 8; ++e) r[e] = (_Float16)(p[e] * sc);
    return r;
}
__device__ __forceinline__ void bar_lgkm() {
    asm volatile("s_waitcnt lgkmcnt(0)\n\ts_barrier" ::: "memory");
}

__global__ __launch_bounds__(512, 2) void lstm_f16(
    const float* __restrict__ x,     // [B, T, D]
    const float* __restrict__ Wih0,  // [256, 32]
    const float* __restrict__ Whh0,  // [256, 64]
    const float* __restrict__ bih0, const float* __restrict__ bhh0,
    const float* __restrict__ Wih1,  // [256, 64]
    const float* __restrict__ Whh1,  // [256, 64]
    const float* __restrict__ bih1, const float* __restrict__ bhh1,
    const float* __restrict__ fc1w,  // [32, 64]
    const float* __restrict__ fc1b,  // [32]
    const float* __restrict__ fc2w,  // [1, 32]
    const float* __restrict__ fc2b,  // [1]
    float* __restrict__ out)         // [B]
{
    // h frag: [parity][kfrag][row = kq*4 + col][e], col = real batch 0..3
    __shared__ __align__(16) _Float16 s_h0[2][2][16][8];  // 1 KB
    __shared__ __align__(16) _Float16 s_h1[2][2][16][8];  // 1 KB
    __shared__ float s_hf[Hh][5];
    __shared__ float s_fcw[32 * 65];
    __shared__ float s_fc[32][5];

    const int tid = threadIdx.x;   // 0..511
    const int w = tid >> 6;        // wave 0..7
    const int l = tid & 63;
    const int ar = l & 15;         // A row within tile
    const int akb = l >> 4;        // k-group
    const int cq = l >> 4;         // C/D row block
    const int cj = l & 15;         // C/D col
    const int cb = cj & 3;         // real batch col
    const int dd = cj >> 2;        // tile select for update (0..3)
    const bool isL1w = (w >= 4);   // wave role: layer 0 or 1
    const int wl = w & 3;
    const int b0 = blockIdx.x * 4;

    // ---- persistent A fragments (log2e folded), 4 tiles x 4 k-slots ----
    // tile i, A-row ar -> weight row g = (ar&3)*64 + 16*wl + 4*(ar>>2) + i
    const int r4 = ar & 3;
    const float sc = (r4 == 2) ? 2.0f * LOG2E : LOG2E;
    const int grow = r4 * 64 + 16 * wl + 4 * (ar >> 2);
    f16x8 Afr[4][4];
    if (!isL1w) {
#pragma unroll
        for (int i = 0; i < 4; ++i) {
            const int g = grow + i;
            Afr[i][0] = cvt8s(Wih0 + g * Dd + akb * 8, sc);       // x
            Afr[i][1] = cvt8s(Whh0 + g * Hh + akb * 8, sc);       // h0 k0-31
            Afr[i][2] = cvt8s(Whh0 + g * Hh + 32 + akb * 8, sc);  // h0 k32-63
            Afr[i][3] = Afr[i][1];                                 // unused
        }
    } else {
#pragma unroll
        for (int i = 0; i < 4; ++i) {
            const int g = grow + i;
            Afr[i][0] = cvt8s(Wih1 + g * Hh + akb * 8, sc);       // h0 k0-31
            Afr[i][1] = cvt8s(Wih1 + g * Hh + 32 + akb * 8, sc);  // h0 k32-63
            Afr[i][2] = cvt8s(Whh1 + g * Hh + akb * 8, sc);       // h1 k0-31
            Afr[i][3] = cvt8s(Whh1 + g * Hh + 32 + akb * 8, sc);  // h1 k32-63
        }
    }

    // bias as crit-chain C-init: biasT[i][r] = gate r of unit 16wl+4cq+i
    const float* bi = isL1w ? bih1 : bih0;
    const float* bhp = isL1w ? bhh1 : bhh0;
    f32x4 biasT[4];
#pragma unroll
    for (int i = 0; i < 4; ++i)
#pragma unroll
        for (int r = 0; r < 4; ++r) {
            const float s2 = (r == 2) ? 2.0f * LOG2E : LOG2E;
            const int uu = 16 * wl + 4 * cq + i;
            biasT[i][r] = s2 * (bi[r * 64 + uu] + bhp[r * 64 + uu]);
        }

    // lane's update target: unit ub (its layer), col cb
    const int ub = 16 * wl + 4 * cq + dd;
    const int kf_h = ub >> 5;
    const int row_h = ((ub & 31) >> 3) * 4 + cb;
    const int e_h = ub & 7;
    _Float16* const wsel = isL1w ? &s_h1[1][kf_h][row_h][e_h]
                                 : &s_h0[0][kf_h][row_h][e_h];
    const int wdelta = isL1w ? -256 : 256;  // f16 elems per parity flip

    // b-frag read row: wrap col = l&3 (4-lane broadcast)
    const int rrow = (l >> 4) * 4 + (l & 3);

    // x direct-load base: batch b0+cb, k = akb*8..+7
    const float* xbase = x + ((size_t)(b0 + cb) * Tt) * Dd + akb * 8;

    // zero h frag buffers (256 dwords each)
    if (tid < 256) ((int*)s_h0)[tid] = 0;
    else           ((int*)s_h1)[tid - 256] = 0;

    float4 xr0, xr1;
    f16x8 xcur;
    if (!isL1w) {
        xr0 = *(const float4*)(xbase);
        xr1 = *(const float4*)(xbase + 4);
#pragma unroll
        for (int e = 0; e < 4; ++e) {
            xcur[e] = (_Float16)xr0[e];
            xcur[4 + e] = (_Float16)xr1[e];
        }
        xr0 = *(const float4*)(xbase + Dd);
        xr1 = *(const float4*)(xbase + Dd + 4);
    }
    float cst = 0.f;
    __syncthreads();

    const f32x4 zero4 = {0.f, 0.f, 0.f, 0.f};

#pragma unroll 2
    for (int t = 0; t < Tt; ++t) {
        const int pr = t & 1;

        f32x4 acc[4];
        if (!isL1w) {
            // (stagger) do x VALU work first so L1 gets the LDS pipe
            f16x8 xn;
#pragma unroll
            for (int e = 0; e < 4; ++e) {
                xn[e] = (_Float16)xr0[e];
                xn[4 + e] = (_Float16)xr1[e];
            }
            const int tf = (t + 2 < Tt) ? (t + 2) : (Tt - 1);
            xr0 = *(const float4*)(xbase + (size_t)tf * Dd);
            xr1 = *(const float4*)(xbase + (size_t)tf * Dd + 4);

            const f16x8 b0a = *(const f16x8*)&s_h0[pr ^ 1][0][rrow][0];
            const f16x8 b0b = *(const f16x8*)&s_h0[pr ^ 1][1][rrow][0];
#pragma unroll
            for (int i = 0; i < 4; ++i) {
                // crit chain: 2 MFMA on h0 (bias-seeded)
                f32x4 q = mfma(Afr[i][1], b0a, biasT[i]);
                q = mfma(Afr[i][2], b0b, q);
                // off-chain: x part
                const f32x4 p = mfma(Afr[i][0], xcur, zero4);
                acc[i] = q + p;
            }
            xcur = xn;
        } else {
            // (stagger) L1 issues all 4 reads immediately
            const f16x8 b1a = *(const f16x8*)&s_h1[pr][0][rrow][0];      // h1(t-2)
            const f16x8 b1b = *(const f16x8*)&s_h1[pr][1][rrow][0];
            const f16x8 b0a = *(const f16x8*)&s_h0[pr ^ 1][0][rrow][0];  // h0(t-1)
            const f16x8 b0b = *(const f16x8*)&s_h0[pr ^ 1][1][rrow][0];
#pragma unroll
            for (int i = 0; i < 4; ++i) {
                // crit chain: 2 MFMA on h1 (bias-seeded)
                f32x4 q = mfma(Afr[i][2], b1a, biasT[i]);
                q = mfma(Afr[i][3], b1b, q);
                // parallel: h0 part (zero-seeded)
                f32x4 p = mfma(Afr[i][0], b0a, zero4);
                p = mfma(Afr[i][1], b0b, p);
                acc[i] = q + p;
            }
        }

        // select this lane's tile (static indices -> cndmask)
        const f32x4 g01 = (dd & 1) ? acc[1] : acc[0];
        const f32x4 g23 = (dd & 1) ? acc[3] : acc[2];
        const f32x4 gg = (dd & 2) ? g23 : g01;

        const float gi = sigm_s(gg[0]);
        const float gf = sigm_s(gg[1]);
        const float zz = tanh_s(gg[2]);
        const float go = sigm_s(gg[3]);
        float cn = gf * cst + gi * zz;
        // hv = go * tanh(cn) = fma(-2*go, rcp(exp2(2L*cn)+1), go)
        float hv = fmaf(-2.0f * go,
                        rcpf(exp2f_(cn * (2.0f * LOG2E)) + 1.0f), go);
        if (t == 0) {  // L1's warm-up output must be zero
            cn = isL1w ? 0.f : cn;
            hv = isL1w ? 0.f : hv;
        }
        cst = cn;
        *(wsel + (pr ? wdelta : 0)) = (_Float16)hv;
        bar_lgkm();
    }

    // ---- epilogue: final L1 step -> h1(511) from h0(511), h1(510) ----
    if (isL1w) {
        const f16x8 b1a = *(const f16x8*)&s_h1[0][0][rrow][0];
        const f16x8 b1b = *(const f16x8*)&s_h1[0][1][rrow][0];
        const f16x8 b0a = *(const f16x8*)&s_h0[1][0][rrow][0];
        const f16x8 b0b = *(const f16x8*)&s_h0[1][1][rrow][0];
        f32x4 acc[4];
#pragma unroll
        for (int i = 0; i < 4; ++i) {
            f32x4 q = mfma(Afr[i][2], b1a, biasT[i]);
            q = mfma(Afr[i][3], b1b, q);
            f32x4 p = mfma(Afr[i][0], b0a, zero4);
            p = mfma(Afr[i][1], b0b, p);
            acc[i] = q + p;
        }
        const f32x4 g01 = (dd & 1) ? acc[1] : acc[0];
        const f32x4 g23 = (dd & 1) ? acc[3] : acc[2];
        const f32x4 gg = (dd & 2) ? g23 : g01;
        const float gi = sigm_s(gg[0]);
        const float gf = sigm_s(gg[1]);
        const float zz = tanh_s(gg[2]);
        const float go = sigm_s(gg[3]);
        const float cn = gf * cst + gi * zz;
        const float hv = fmaf(-2.0f * go,
                              rcpf(exp2f_(cn * (2.0f * LOG2E)) + 1.0f), go);
        s_hf[ub][cb] = hv;
    }
    __syncthreads();

    // ---- FC epilogue (4 batches) ----
    for (int i2 = tid; i2 < 32 * 64; i2 += 512) {
        const int m = i2 >> 6, uu = i2 & 63;
        s_fcw[m * 65 + uu] = fc1w[i2];
    }
    __syncthreads();
    if (tid < 128) {
        const int m = tid >> 2, jj = tid & 3;
        float acc = fc1b[m];
#pragma unroll
        for (int uu = 0; uu < Hh; ++uu)
            acc = fmaf(s_fcw[m * 65 + uu], s_hf[uu][jj], acc);
        s_fc[m][jj] = fmaxf(acc, 0.f);
    }
    __syncthreads();
    if (tid < 4) {
        float acc = fc2b[0];
#pragma unroll
        for (int m = 0; m < 32; ++m)
            acc = fmaf(fc2w[m], s_fc[m][tid], acc);
        out[b0 + tid] = acc;
    }
}

}  // namespace

extern "C" void kernel_launch(void* const* d_in, const int* in_sizes, int n_in,
                              void* d_out, int out_size, void* d_ws, size_t ws_size,
                              hipStream_t stream) {
    const float* x    = (const float*)d_in[0];
    const float* Wih0 = (const float*)d_in[1];
    const float* Whh0 = (const float*)d_in[2];
    const float* bih0 = (const float*)d_in[3];
    const float* bhh0 = (const float*)d_in[4];
    const float* Wih1 = (const float*)d_in[5];
    const float* Whh1 = (const float*)d_in[6];
    const float* bih1 = (const float*)d_in[7];
    const float* bhh1 = (const float*)d_in[8];
    const float* fc1w = (const float*)d_in[9];
    const float* fc1b = (const float*)d_in[10];
    const float* fc2w = (const float*)d_in[11];
    const float* fc2b = (const float*)d_in[12];
    float* out = (float*)d_out;

    lstm_f16<<<dim3(256), dim3(512), 0, stream>>>(
        x, Wih0, Whh0, bih0, bhh0, Wih1, Whh1, bih1, bhh1,
        fc1w, fc1b, fc2w, fc2b, out);
}